// Round 6
// baseline (156.246 us; speedup 1.0000x reference)
//
#include <hip/hip_runtime.h>

// EntityLinker forward, MI355X/gfx950. One block per batch b, 256 thr (4 waves).
// R6 (tier A): LDS exactly 32768 (CH+QH) -> 4-5 blocks/CU, no grid tail.
//   att routed through global ws (8KB/block, L2-resident); qsum partials via
//   wave-shfl + overlay in att slice; out via b_o-init + atomicAdd (P6 gone).
// Tier B/C fallback = R5 kernel verbatim (att in LDS, 40960B) if ws too small.

typedef __attribute__((ext_vector_type(8))) short     short8;
typedef __attribute__((ext_vector_type(8))) __bf16    bf16x8;
typedef __attribute__((ext_vector_type(4))) float     f32x4;
typedef __attribute__((ext_vector_type(4))) int       int4v;

#define SWZ8(row, off) ((off) ^ (((row) & 7) << 4))
#define SWZQ(row, off) ((off) ^ (((row) & 7) << 4) ^ ((((row) >> 3) & 3) << 5))

// ---- tier A LDS: 32768 B ----
#define A_CH   0        // c_h [64][128] bf16, 256B rows, SWZ8
#define A_QH   16384    // q_h [64][128] bf16, 256B rows, SWZQ -> wq after P4
#define A_LDS  32768

// ---- tier B LDS: 40960 B (R5) ----
#define CH_OFF  0
#define QH_OFF  16384
#define X_OFF   32768
#define LDS_SIZE 40960

__device__ __forceinline__ unsigned short f2bf(float x) {
    __bf16 h = (__bf16)x;
    return __builtin_bit_cast(unsigned short, h);
}
__device__ __forceinline__ float bf2f(unsigned short u) {
    return __builtin_bit_cast(float, ((unsigned)u) << 16);
}
__device__ __forceinline__ float bflo(unsigned u) {
    return __builtin_bit_cast(float, u << 16);
}
__device__ __forceinline__ float bfhi(unsigned u) {
    return __builtin_bit_cast(float, u & 0xFFFF0000u);
}
__device__ __forceinline__ unsigned pk2(float a, float b) {
    return (unsigned)f2bf(a) | ((unsigned)f2bf(b) << 16);
}
__device__ __forceinline__ f32x4 mfma16(short8 a, short8 b, f32x4 c) {
    return __builtin_amdgcn_mfma_f32_16x16x32_bf16(
        __builtin_bit_cast(bf16x8, a), __builtin_bit_cast(bf16x8, b), c, 0, 0, 0);
}

// W_h [640][128] f32 -> whT [128][640] bf16.
__global__ __launch_bounds__(256) void el_prep(const float* __restrict__ W_h,
                                               unsigned short* __restrict__ whT) {
    int t = blockIdx.x * 256 + threadIdx.x;
    int k = t >> 7, n = t & 127;
    whT[n * 640 + k] = f2bf(W_h[t]);
}

// embed f32 [100000][128] -> bf16 table in ws.
__global__ __launch_bounds__(256) void el_conv(const float* __restrict__ e,
                                               unsigned short* __restrict__ ebf) {
    long i = ((long)blockIdx.x * 256 + threadIdx.x) * 8;
    f32x4 a = *(const f32x4*)(e + i);
    f32x4 c = *(const f32x4*)(e + i + 4);
    uint4 pk;
    pk.x = pk2(a[0], a[1]); pk.y = pk2(a[2], a[3]);
    pk.z = pk2(c[0], c[1]); pk.w = pk2(c[2], c[3]);
    *(uint4*)(ebf + i) = pk;
}

// ======================= tier A =======================
__global__ __launch_bounds__(256, 4) void el_main_a(
    const int* __restrict__ q_ids, const int* __restrict__ c_ids,
    const int* __restrict__ num_qs,
    const unsigned short* __restrict__ ebf,
    const unsigned short* __restrict__ whT,
    unsigned short* __restrict__ qsum_ws,
    unsigned short* __restrict__ att_ws,      // [1024][4096] shorts (8KB/b)
    const float* __restrict__ b_h,
    const float* __restrict__ W_o, const float* __restrict__ b_o,
    float* __restrict__ out)
{
    __shared__ __align__(16) char smem[A_LDS];
    const int tid = threadIdx.x;
    const int b = blockIdx.x;
    const int nq = num_qs[b] > 0 ? num_qs[b] : 1;
    unsigned short* batt = att_ws + (size_t)b * 4096;
    float* bqp = (float*)batt;                // qpart overlay [4][128] f32

    // ---- P0: out init (poisoned 0xAA each call) ----
    if (tid < 64) out[(b << 6) + tid] = b_o[0];

    // ---- P1: gathers ----
    {
        const int l4 = tid & 15, gg = tid >> 4;
        #pragma unroll 2
        for (int cc = 0; cc < 4; ++cc) {
            const int c = gg + cc * 16;
            const int* idp = c_ids + (((b << 6) + c) << 3);
            int4v i0 = *(const int4v*)idp, i1 = *(const int4v*)(idp + 4);
            int id8[8] = {i0[0], i0[1], i0[2], i0[3], i1[0], i1[1], i1[2], i1[3]};
            int cnt = 0;
            #pragma unroll
            for (int t = 0; t < 8; ++t) cnt += (id8[t] != 0);
            float acc[8] = {0.f,0.f,0.f,0.f,0.f,0.f,0.f,0.f};
            #pragma unroll
            for (int t = 0; t < 8; ++t) {
                uint4 v = *(const uint4*)(ebf + (long)id8[t] * 128 + l4 * 8);
                acc[0] += bflo(v.x); acc[1] += bfhi(v.x);
                acc[2] += bflo(v.y); acc[3] += bfhi(v.y);
                acc[4] += bflo(v.z); acc[5] += bfhi(v.z);
                acc[6] += bflo(v.w); acc[7] += bfhi(v.w);
            }
            float inv = 1.0f / (float)(cnt > 0 ? cnt : 1);
            uint4 pk;
            pk.x = pk2(acc[0]*inv, acc[1]*inv); pk.y = pk2(acc[2]*inv, acc[3]*inv);
            pk.z = pk2(acc[4]*inv, acc[5]*inv); pk.w = pk2(acc[6]*inv, acc[7]*inv);
            *(uint4*)(smem + A_CH + SWZ8(c, c * 256 + l4 * 16)) = pk;
        }
        float qa[8] = {0.f,0.f,0.f,0.f,0.f,0.f,0.f,0.f};
        #pragma unroll
        for (int qq = 0; qq < 4; ++qq) {
            const int q = gg + (qq << 4);
            int id = q_ids[(b << 6) + q];
            uint4 v = *(const uint4*)(ebf + (long)id * 128 + l4 * 8);
            *(uint4*)(smem + A_QH + SWZQ(q, q * 256 + l4 * 16)) = v;
            if (q < nq) {
                qa[0] += bflo(v.x); qa[1] += bfhi(v.x);
                qa[2] += bflo(v.y); qa[3] += bfhi(v.y);
                qa[4] += bflo(v.z); qa[5] += bfhi(v.z);
                qa[6] += bflo(v.w); qa[7] += bfhi(v.w);
            }
        }
        // combine the wave's 4 gather-groups in-register
        #pragma unroll
        for (int e = 0; e < 8; ++e) {
            qa[e] += __shfl_xor(qa[e], 16);
            qa[e] += __shfl_xor(qa[e], 32);
        }
        const int lane = tid & 63, w = tid >> 6;
        if (lane < 16) {
            *(f32x4*)(bqp + w * 128 + lane * 8)     = (f32x4){qa[0],qa[1],qa[2],qa[3]};
            *(f32x4*)(bqp + w * 128 + lane * 8 + 4) = (f32x4){qa[4],qa[5],qa[6],qa[7]};
        }
    }
    __syncthreads();

    // ---- P2: qsum -> global ws (bf16) ----
    if (tid < 128) {
        float s = bqp[tid] + bqp[128 + tid] + bqp[256 + tid] + bqp[384 + tid];
        qsum_ws[(b << 7) + tid] = f2bf(s / (float)nq);
    }
    __syncthreads();   // qpart region consumed before att overwrites it

    const int lane = tid & 63, w = tid >> 6;
    const int lr = lane & 15, lg = lane >> 4;

    // ---- P3: sim + in-reg softmax -> att to global ----
    {
        short8 a[4];
        const int arow = w * 16 + lr;
        #pragma unroll
        for (int s = 0; s < 4; ++s)
            a[s] = *(const short8*)(smem + A_CH + SWZ8(arow, arow * 256 + s * 64 + lg * 16));
        f32x4 sim[4];
        #pragma unroll
        for (int ct = 0; ct < 4; ++ct) {
            f32x4 acc = {0.f, 0.f, 0.f, 0.f};
            const int q = ct * 16 + lr;
            #pragma unroll
            for (int s = 0; s < 4; ++s) {
                short8 bf = *(const short8*)(smem + A_QH + SWZQ(q, q * 256 + s * 64 + lg * 16));
                acc = mfma16(a[s], bf, acc);
            }
            sim[ct] = acc;
        }
        const float scale = 0.08838834764831845f;  // 1/sqrt(128)
        #pragma unroll
        for (int ct = 0; ct < 4; ++ct) {
            const int q = ct * 16 + lr;
            #pragma unroll
            for (int r = 0; r < 4; ++r)
                sim[ct][r] = (q < nq) ? sim[ct][r] * scale : -3.0e38f;
        }
        float mx[4], sm[4];
        #pragma unroll
        for (int r = 0; r < 4; ++r)
            mx[r] = fmaxf(fmaxf(sim[0][r], sim[1][r]), fmaxf(sim[2][r], sim[3][r]));
        #pragma unroll
        for (int off = 1; off <= 8; off <<= 1)
            #pragma unroll
            for (int r = 0; r < 4; ++r)
                mx[r] = fmaxf(mx[r], __shfl_xor(mx[r], off));
        #pragma unroll
        for (int ct = 0; ct < 4; ++ct)
            #pragma unroll
            for (int r = 0; r < 4; ++r)
                sim[ct][r] = __expf(sim[ct][r] - mx[r]);
        #pragma unroll
        for (int r = 0; r < 4; ++r)
            sm[r] = (sim[0][r] + sim[1][r]) + (sim[2][r] + sim[3][r]);
        #pragma unroll
        for (int off = 1; off <= 8; off <<= 1)
            #pragma unroll
            for (int r = 0; r < 4; ++r)
                sm[r] += __shfl_xor(sm[r], off);
        const int cbase = w * 16 + lg * 4;
        #pragma unroll
        for (int ct = 0; ct < 4; ++ct)
            #pragma unroll
            for (int r = 0; r < 4; ++r) {
                int c = cbase + r, q = ct * 16 + lr;
                batt[c * 64 + q] = f2bf(sim[ct][r] * (1.0f / sm[r]));
            }
    }
    __syncthreads();   // barrier drains vmem -> att visible in L2

    // ---- P4: weighted_q = att @ q_h ----
    f32x4 wqa[8];
    {
        short8 pa[2];
        const int prow = w * 16 + lr;
        #pragma unroll
        for (int s = 0; s < 2; ++s)
            pa[s] = *(const short8*)(batt + prow * 64 + s * 32 + lg * 8);
        #pragma unroll
        for (int ct = 0; ct < 8; ++ct) {
            f32x4 acc = {0.f, 0.f, 0.f, 0.f};
            const int d = ct * 16 + lr;
            const int dlx = (d << 1) ^ (lg << 5);
            #pragma unroll
            for (int s = 0; s < 2; ++s) {
                const int qbase = (s << 5) + (lg << 3);
                short8 bf;
                #pragma unroll
                for (int j = 0; j < 8; ++j) {
                    int off = A_QH + ((qbase + j) << 8) + (dlx ^ (j << 4));
                    bf[j] = *(const short*)(smem + off);
                }
                acc = mfma16(pa[s], bf, acc);
            }
            wqa[ct] = acc;
        }
    }
    __syncthreads();   // all q_h reads done -> wq overwrites QH
    {
        const int cbase = w * 16 + lg * 4;
        #pragma unroll
        for (int ct = 0; ct < 8; ++ct)
            #pragma unroll
            for (int r = 0; r < 4; ++r) {
                int c = cbase + r, d = ct * 16 + lr;
                *(unsigned short*)(smem + A_QH + SWZQ(c, c * 256 + d * 2)) =
                    f2bf(wqa[ct][r]);
            }
    }
    __syncthreads();

    // ---- P5: column-split GEMM + tanh + W_o -> atomic out ----
    {
        f32x4 acc[4][2];
        #pragma unroll
        for (int rt = 0; rt < 4; ++rt) {
            acc[rt][0] = (f32x4){0.f, 0.f, 0.f, 0.f};
            acc[rt][1] = (f32x4){0.f, 0.f, 0.f, 0.f};
        }
        const int n0 = w * 32 + lr, n1 = n0 + 16;
        const int klane = lg * 8;
        short8 qsf[4];
        #pragma unroll
        for (int sk = 0; sk < 4; ++sk)
            qsf[sk] = *(const short8*)(qsum_ws + (b << 7) + sk * 32 + klane);
        const float bh0 = b_h[n0], bh1 = b_h[n1];
        const float wo0 = W_o[n0], wo1 = W_o[n1];

        for (int sk = 0; sk < 4; ++sk) {
            short8 B0[5], B1[5];
            #pragma unroll
            for (int p = 0; p < 5; ++p) {
                B0[p] = *(const short8*)(whT + n0 * 640 + p * 128 + sk * 32 + klane);
                B1[p] = *(const short8*)(whT + n1 * 640 + p * 128 + sk * 32 + klane);
            }
            #pragma unroll
            for (int rt = 0; rt < 4; ++rt) {
                const int row = rt * 16 + lr;
                short8 chf = *(const short8*)(smem + A_CH + SWZ8(row, row * 256 + sk * 64 + lg * 16));
                short8 wqf = *(const short8*)(smem + A_QH + SWZQ(row, row * 256 + sk * 64 + lg * 16));
                short8 prf, adf;
                #pragma unroll
                for (int e = 0; e < 8; ++e) {
                    float cv = bf2f((unsigned short)chf[e]);
                    float wv = bf2f((unsigned short)wqf[e]);
                    prf[e] = (short)f2bf(cv * wv);
                    adf[e] = (short)f2bf(fabsf(cv - wv));
                }
                acc[rt][0] = mfma16(qsf[sk], B0[0], acc[rt][0]);
                acc[rt][1] = mfma16(qsf[sk], B1[0], acc[rt][1]);
                acc[rt][0] = mfma16(chf,     B0[1], acc[rt][0]);
                acc[rt][1] = mfma16(chf,     B1[1], acc[rt][1]);
                acc[rt][0] = mfma16(wqf,     B0[2], acc[rt][0]);
                acc[rt][1] = mfma16(wqf,     B1[2], acc[rt][1]);
                acc[rt][0] = mfma16(prf,     B0[3], acc[rt][0]);
                acc[rt][1] = mfma16(prf,     B1[3], acc[rt][1]);
                acc[rt][0] = mfma16(adf,     B0[4], acc[rt][0]);
                acc[rt][1] = mfma16(adf,     B1[4], acc[rt][1]);
            }
        }

        #pragma unroll
        for (int rt = 0; rt < 4; ++rt)
            #pragma unroll
            for (int r = 0; r < 4; ++r) {
                float x0 = acc[rt][0][r] + bh0;
                float x1 = acc[rt][1][r] + bh1;
                float t0 = 1.0f - 2.0f / (__expf(2.0f * x0) + 1.0f);  // tanh
                float t1 = 1.0f - 2.0f / (__expf(2.0f * x1) + 1.0f);
                float po = t0 * wo0 + t1 * wo1;
                #pragma unroll
                for (int off = 1; off <= 8; off <<= 1)
                    po += __shfl_xor(po, off);
                if (lr == 0)
                    atomicAdd(out + (b << 6) + rt * 16 + lg * 4 + r, po);
            }
    }
}

// ======================= tier B/C (R5 verbatim) =======================
template <bool BF16E>
__global__ __launch_bounds__(256, 4) void el_main_b(
    const int* __restrict__ q_ids, const int* __restrict__ c_ids,
    const int* __restrict__ num_qs, const float* __restrict__ emb,
    const unsigned short* __restrict__ ebf,
    const unsigned short* __restrict__ whT,
    unsigned short* __restrict__ qsum_ws,
    const float* __restrict__ b_h,
    const float* __restrict__ W_o, const float* __restrict__ b_o,
    float* __restrict__ out)
{
    __shared__ __align__(16) char smem[LDS_SIZE];
    const int tid = threadIdx.x;
    const int b = blockIdx.x;
    const int nq = num_qs[b] > 0 ? num_qs[b] : 1;

    {
        const int l4 = tid & 15, gg = tid >> 4;
        #pragma unroll 2
        for (int cc = 0; cc < 4; ++cc) {
            const int c = gg + cc * 16;
            const int* idp = c_ids + (((b << 6) + c) << 3);
            int4v i0 = *(const int4v*)idp, i1 = *(const int4v*)(idp + 4);
            int id8[8] = {i0[0], i0[1], i0[2], i0[3], i1[0], i1[1], i1[2], i1[3]};
            int cnt = 0;
            #pragma unroll
            for (int t = 0; t < 8; ++t) cnt += (id8[t] != 0);
            float acc[8] = {0.f,0.f,0.f,0.f,0.f,0.f,0.f,0.f};
            #pragma unroll
            for (int t = 0; t < 8; ++t) {
                if constexpr (BF16E) {
                    uint4 v = *(const uint4*)(ebf + (long)id8[t] * 128 + l4 * 8);
                    acc[0] += bflo(v.x); acc[1] += bfhi(v.x);
                    acc[2] += bflo(v.y); acc[3] += bfhi(v.y);
                    acc[4] += bflo(v.z); acc[5] += bfhi(v.z);
                    acc[6] += bflo(v.w); acc[7] += bfhi(v.w);
                } else {
                    f32x4 lo = *(const f32x4*)(emb + (long)id8[t] * 128 + l4 * 8);
                    f32x4 hi = *(const f32x4*)(emb + (long)id8[t] * 128 + l4 * 8 + 4);
                    acc[0] += lo[0]; acc[1] += lo[1]; acc[2] += lo[2]; acc[3] += lo[3];
                    acc[4] += hi[0]; acc[5] += hi[1]; acc[6] += hi[2]; acc[7] += hi[3];
                }
            }
            float inv = 1.0f / (float)(cnt > 0 ? cnt : 1);
            uint4 pk;
            pk.x = pk2(acc[0]*inv, acc[1]*inv); pk.y = pk2(acc[2]*inv, acc[3]*inv);
            pk.z = pk2(acc[4]*inv, acc[5]*inv); pk.w = pk2(acc[6]*inv, acc[7]*inv);
            *(uint4*)(smem + CH_OFF + SWZ8(c, c * 256 + l4 * 16)) = pk;
        }
        float qa[8] = {0.f,0.f,0.f,0.f,0.f,0.f,0.f,0.f};
        #pragma unroll
        for (int qq = 0; qq < 4; ++qq) {
            const int q = gg + (qq << 4);
            int id = q_ids[(b << 6) + q];
            uint4 v;
            if constexpr (BF16E) {
                v = *(const uint4*)(ebf + (long)id * 128 + l4 * 8);
            } else {
                f32x4 lo = *(const f32x4*)(emb + (long)id * 128 + l4 * 8);
                f32x4 hi = *(const f32x4*)(emb + (long)id * 128 + l4 * 8 + 4);
                v.x = pk2(lo[0], lo[1]); v.y = pk2(lo[2], lo[3]);
                v.z = pk2(hi[0], hi[1]); v.w = pk2(hi[2], hi[3]);
            }
            *(uint4*)(smem + QH_OFF + SWZQ(q, q * 256 + l4 * 16)) = v;
            if (q < nq) {
                qa[0] += bflo(v.x); qa[1] += bfhi(v.x);
                qa[2] += bflo(v.y); qa[3] += bfhi(v.y);
                qa[4] += bflo(v.z); qa[5] += bfhi(v.z);
                qa[6] += bflo(v.w); qa[7] += bfhi(v.w);
            }
        }
        float* qsp = (float*)(smem + X_OFF);
        *(f32x4*)(qsp + gg * 128 + l4 * 8)     = (f32x4){qa[0], qa[1], qa[2], qa[3]};
        *(f32x4*)(qsp + gg * 128 + l4 * 8 + 4) = (f32x4){qa[4], qa[5], qa[6], qa[7]};
    }
    __syncthreads();

    if (tid < 128) {
        const float* qsp = (const float*)(smem + X_OFF);
        float s = 0.f;
        #pragma unroll
        for (int g = 0; g < 16; ++g) s += qsp[g * 128 + tid];
        qsum_ws[(b << 7) + tid] = f2bf(s / (float)nq);
    }
    __syncthreads();

    const int lane = tid & 63, w = tid >> 6;
    const int lr = lane & 15, lg = lane >> 4;

    {
        short8 a[4];
        const int arow = w * 16 + lr;
        #pragma unroll
        for (int s = 0; s < 4; ++s)
            a[s] = *(const short8*)(smem + CH_OFF + SWZ8(arow, arow * 256 + s * 64 + lg * 16));
        f32x4 sim[4];
        #pragma unroll
        for (int ct = 0; ct < 4; ++ct) {
            f32x4 acc = {0.f, 0.f, 0.f, 0.f};
            const int q = ct * 16 + lr;
            #pragma unroll
            for (int s = 0; s < 4; ++s) {
                short8 bf = *(const short8*)(smem + QH_OFF + SWZQ(q, q * 256 + s * 64 + lg * 16));
                acc = mfma16(a[s], bf, acc);
            }
            sim[ct] = acc;
        }
        const float scale = 0.08838834764831845f;
        #pragma unroll
        for (int ct = 0; ct < 4; ++ct) {
            const int q = ct * 16 + lr;
            #pragma unroll
            for (int r = 0; r < 4; ++r)
                sim[ct][r] = (q < nq) ? sim[ct][r] * scale : -3.0e38f;
        }
        float mx[4], sm[4];
        #pragma unroll
        for (int r = 0; r < 4; ++r)
            mx[r] = fmaxf(fmaxf(sim[0][r], sim[1][r]), fmaxf(sim[2][r], sim[3][r]));
        #pragma unroll
        for (int off = 1; off <= 8; off <<= 1)
            #pragma unroll
            for (int r = 0; r < 4; ++r)
                mx[r] = fmaxf(mx[r], __shfl_xor(mx[r], off));
        #pragma unroll
        for (int ct = 0; ct < 4; ++ct)
            #pragma unroll
            for (int r = 0; r < 4; ++r)
                sim[ct][r] = __expf(sim[ct][r] - mx[r]);
        #pragma unroll
        for (int r = 0; r < 4; ++r)
            sm[r] = (sim[0][r] + sim[1][r]) + (sim[2][r] + sim[3][r]);
        #pragma unroll
        for (int off = 1; off <= 8; off <<= 1)
            #pragma unroll
            for (int r = 0; r < 4; ++r)
                sm[r] += __shfl_xor(sm[r], off);
        const int cbase = w * 16 + lg * 4;
        #pragma unroll
        for (int ct = 0; ct < 4; ++ct)
            #pragma unroll
            for (int r = 0; r < 4; ++r) {
                int c = cbase + r, q = ct * 16 + lr;
                *(unsigned short*)(smem + X_OFF + SWZ8(c, c * 128 + q * 2)) =
                    f2bf(sim[ct][r] * (1.0f / sm[r]));
            }
    }
    __syncthreads();

    f32x4 wqa[8];
    {
        short8 pa[2];
        const int arow = w * 16 + lr;
        #pragma unroll
        for (int s = 0; s < 2; ++s)
            pa[s] = *(const short8*)(smem + X_OFF + SWZ8(arow, arow * 128 + s * 64 + lg * 16));
        #pragma unroll
        for (int ct = 0; ct < 8; ++ct) {
            f32x4 acc = {0.f, 0.f, 0.f, 0.f};
            const int d = ct * 16 + lr;
            const int dlx = (d << 1) ^ (lg << 5);
            #pragma unroll
            for (int s = 0; s < 2; ++s) {
                const int qbase = (s << 5) + (lg << 3);
                short8 bf;
                #pragma unroll
                for (int j = 0; j < 8; ++j) {
                    int off = QH_OFF + ((qbase + j) << 8) + (dlx ^ (j << 4));
                    bf[j] = *(const short*)(smem + off);
                }
                acc = mfma16(pa[s], bf, acc);
            }
            wqa[ct] = acc;
        }
    }
    __syncthreads();
    {
        const int cbase = w * 16 + lg * 4;
        #pragma unroll
        for (int ct = 0; ct < 8; ++ct)
            #pragma unroll
            for (int r = 0; r < 4; ++r) {
                int c = cbase + r, d = ct * 16 + lr;
                *(unsigned short*)(smem + QH_OFF + SWZQ(c, c * 256 + d * 2)) =
                    f2bf(wqa[ct][r]);
            }
    }
    __syncthreads();

    {
        f32x4 acc[4][2];
        #pragma unroll
        for (int rt = 0; rt < 4; ++rt) {
            acc[rt][0] = (f32x4){0.f, 0.f, 0.f, 0.f};
            acc[rt][1] = (f32x4){0.f, 0.f, 0.f, 0.f};
        }
        const int n0 = w * 32 + lr, n1 = n0 + 16;
        const int klane = lg * 8;
        short8 qsf[4];
        #pragma unroll
        for (int sk = 0; sk < 4; ++sk)
            qsf[sk] = *(const short8*)(qsum_ws + (b << 7) + sk * 32 + klane);
        const float bh0 = b_h[n0], bh1 = b_h[n1];
        const float wo0 = W_o[n0], wo1 = W_o[n1];

        for (int sk = 0; sk < 4; ++sk) {
            short8 B0[5], B1[5];
            #pragma unroll
            for (int p = 0; p < 5; ++p) {
                B0[p] = *(const short8*)(whT + n0 * 640 + p * 128 + sk * 32 + klane);
                B1[p] = *(const short8*)(whT + n1 * 640 + p * 128 + sk * 32 + klane);
            }
            #pragma unroll
            for (int rt = 0; rt < 4; ++rt) {
                const int row = rt * 16 + lr;
                short8 chf = *(const short8*)(smem + CH_OFF + SWZ8(row, row * 256 + sk * 64 + lg * 16));
                short8 wqf = *(const short8*)(smem + QH_OFF + SWZQ(row, row * 256 + sk * 64 + lg * 16));
                short8 prf, adf;
                #pragma unroll
                for (int e = 0; e < 8; ++e) {
                    float cv = bf2f((unsigned short)chf[e]);
                    float wv = bf2f((unsigned short)wqf[e]);
                    prf[e] = (short)f2bf(cv * wv);
                    adf[e] = (short)f2bf(fabsf(cv - wv));
                }
                acc[rt][0] = mfma16(qsf[sk], B0[0], acc[rt][0]);
                acc[rt][1] = mfma16(qsf[sk], B1[0], acc[rt][1]);
                acc[rt][0] = mfma16(chf,     B0[1], acc[rt][0]);
                acc[rt][1] = mfma16(chf,     B1[1], acc[rt][1]);
                acc[rt][0] = mfma16(wqf,     B0[2], acc[rt][0]);
                acc[rt][1] = mfma16(wqf,     B1[2], acc[rt][1]);
                acc[rt][0] = mfma16(prf,     B0[3], acc[rt][0]);
                acc[rt][1] = mfma16(prf,     B1[3], acc[rt][1]);
                acc[rt][0] = mfma16(adf,     B0[4], acc[rt][0]);
                acc[rt][1] = mfma16(adf,     B1[4], acc[rt][1]);
            }
        }

        #pragma unroll
        for (int rt = 0; rt < 4; ++rt)
            #pragma unroll
            for (int r = 0; r < 4; ++r) {
                float x0 = acc[rt][0][r] + bh0;
                float x1 = acc[rt][1][r] + bh1;
                float t0 = 1.0f - 2.0f / (__expf(2.0f * x0) + 1.0f);
                float t1 = 1.0f - 2.0f / (__expf(2.0f * x1) + 1.0f);
                float po = t0 * wo0 + t1 * wo1;
                #pragma unroll
                for (int off = 1; off <= 8; off <<= 1)
                    po += __shfl_xor(po, off);
                if (lr == 0)
                    *(float*)(smem + X_OFF + (w * 64 + rt * 16 + lg * 4 + r) * 4) = po;
            }
    }
    __syncthreads();

    if (tid < 64) {
        float o = b_o[0];
        #pragma unroll
        for (int w2 = 0; w2 < 4; ++w2)
            o += *(const float*)(smem + X_OFF + (w2 * 64 + tid) * 4);
        out[(b << 6) + tid] = o;
    }
}

extern "C" void kernel_launch(void* const* d_in, const int* in_sizes, int n_in,
                              void* d_out, int out_size, void* d_ws, size_t ws_size,
                              hipStream_t stream) {
    const int*   q_ids  = (const int*)d_in[0];
    const int*   c_ids  = (const int*)d_in[1];
    const int*   num_qs = (const int*)d_in[2];
    // d_in[3] num_cols: unused by the reference forward
    const float* embed  = (const float*)d_in[4];
    const float* W_h    = (const float*)d_in[5];
    const float* b_h    = (const float*)d_in[6];
    const float* W_o    = (const float*)d_in[7];
    const float* b_o    = (const float*)d_in[8];
    float*       out    = (float*)d_out;

    // ws: [0,160K) whT | [160K,416K) qsum | [416K,+25.6M) ebf | +8M att
    const size_t EBF_OFF = 425984;
    const size_t EBF_END = EBF_OFF + (size_t)100000 * 128 * 2;   // 26,025,984
    const size_t ATT_END = EBF_END + (size_t)1024 * 4096 * 2;    // 34,414,592
    unsigned short* whT  = (unsigned short*)d_ws;
    unsigned short* qsum = (unsigned short*)((char*)d_ws + 163840);
    unsigned short* ebf  = (unsigned short*)((char*)d_ws + EBF_OFF);
    unsigned short* attw = (unsigned short*)((char*)d_ws + EBF_END);

    el_prep<<<320, 256, 0, stream>>>(W_h, whT);

    if (ws_size >= ATT_END) {
        el_conv<<<6250, 256, 0, stream>>>(embed, ebf);
        el_main_a<<<1024, 256, 0, stream>>>(q_ids, c_ids, num_qs, ebf, whT,
                                            qsum, attw, b_h, W_o, b_o, out);
    } else if (ws_size >= EBF_END) {
        el_conv<<<6250, 256, 0, stream>>>(embed, ebf);
        el_main_b<true><<<1024, 256, 0, stream>>>(q_ids, c_ids, num_qs, embed, ebf,
                                                  whT, qsum, b_h, W_o, b_o, out);
    } else {
        el_main_b<false><<<1024, 256, 0, stream>>>(q_ids, c_ids, num_qs, embed, ebf,
                                                   whT, qsum, b_h, W_o, b_o, out);
    }
}